// Round 7
// baseline (300.537 us; speedup 1.0000x reference)
//
#include <hip/hip_runtime.h>

#define LSEQ 512
#define BATCH 1024
#define T 48
#define CHUNK 8
#define NCH (LSEQ / CHUNK)   // 64 chunks cover t = 1..512 (t=512 masked off)

static __device__ __forceinline__ float bcast_lane0(float x) {
    return __int_as_float(__builtin_amdgcn_readfirstlane(__float_as_int(x)));
}
static __device__ __forceinline__ float fast_rcp(float x) {
#if __has_builtin(__builtin_amdgcn_rcpf)
    return __builtin_amdgcn_rcpf(x);
#else
    return 1.0f / x;
#endif
}

// zero-instruction register pins (applied ONCE -> values become opaque, the
// compiler can neither rematerialize nor fold them; must keep in VGPRs)
#define PIN4(a,b,c,d) asm volatile("" : "+v"(a), "+v"(b), "+v"(c), "+v"(d))
#define PIN_E(E) do { \
    PIN4(E[ 0],E[ 1],E[ 2],E[ 3]); PIN4(E[ 4],E[ 5],E[ 6],E[ 7]); \
    PIN4(E[ 8],E[ 9],E[10],E[11]); PIN4(E[12],E[13],E[14],E[15]); \
    PIN4(E[16],E[17],E[18],E[19]); PIN4(E[20],E[21],E[22],E[23]); \
    PIN4(E[24],E[25],E[26],E[27]); PIN4(E[28],E[29],E[30],E[31]); \
    PIN4(E[32],E[33],E[34],E[35]); PIN4(E[36],E[37],E[38],E[39]); \
    PIN4(E[40],E[41],E[42],E[43]); PIN4(E[44],E[45],E[46],E[47]); \
} while (0)

// One forward step, replicated-W form. Invariant: alpha_j = C + log W[j]
// (W unnormalized but rescaled by 1/W[0] each step -> bounded in f32).
//   S_j  = sum_i W[i]*E[i]          (48 pure-VGPR fmac, no cross-lane)
//   u_j  = exp(em_j-em_0) * S_j / W[0];  C += em_0 + log W[0]   (if mask)
//   lane j writes its u_j to LDS; all lanes read back W[0..47] (broadcast).
static __device__ __forceinline__ void crf_step(
    float W[T], float& w_self, float& C, float em, int mk,
    const float E[T], float* __restrict__ lds, int lane)
{
    const float em0 = bcast_lane0(em);
    const float e   = __expf(em - em0);        // independent of W -> overlaps fmacs
    float s0 = 0.f, s1 = 0.f, s2 = 0.f, s3 = 0.f;
    #pragma unroll
    for (int i = 0; i < T; i += 4) {
        s0 = __builtin_fmaf(W[i + 0], E[i + 0], s0);
        s1 = __builtin_fmaf(W[i + 1], E[i + 1], s1);
        s2 = __builtin_fmaf(W[i + 2], E[i + 2], s2);
        s3 = __builtin_fmaf(W[i + 3], E[i + 3], s3);
    }
    const float S    = (s0 + s1) + (s2 + s3);
    const float rs   = fast_rcp(W[0]);         // W[0] > 0 always
    const float lg   = __logf(W[0]);           // off the S-chain (known early)
    const float unew = (e * rs) * S;
    const bool  upd  = (mk != 0);
    w_self = upd ? unew : w_self;
    C      = upd ? (C + em0 + lg) : C;
    lds[lane] = w_self;                        // ds_write_b32, banks 0..63 distinct
    #pragma unroll
    for (int k = 0; k < T / 4; ++k) {          // 12x ds_read_b128, same addr on all
        const float4 v = ((const float4*)lds)[k];   // lanes -> broadcast, no conflict
        W[4 * k + 0] = v.x; W[4 * k + 1] = v.y;
        W[4 * k + 2] = v.z; W[4 * k + 3] = v.w;
    }
}

// ---------------------------------------------------------------------------
// Kernel 1: forward algorithm (denominator). One wave per batch element.
// Lane j owns output state j; the 48-dim alpha (as unnormalized W) is
// REPLICATED in every lane's registers, refreshed per step via one LDS write +
// 12 broadcast float4 reads. No readlane/SGPR hazards, no barriers, E pinned
// opaque in 48 VGPRs, emissions/mask double-buffered 8 steps ahead.
// ---------------------------------------------------------------------------
__global__ __launch_bounds__(256, 1) void crf_forward(
    const float* __restrict__ emissions,      // (L,B,T)
    const int* __restrict__ mask,             // (L,B) bool->int32
    const float* __restrict__ start_tr,       // (T)
    const float* __restrict__ end_tr,         // (T)
    const float* __restrict__ trans,          // (T,T)
    float* __restrict__ denom_out)            // (B)
{
    __shared__ float Wlds[4][64];
    const int tid  = threadIdx.x;
    const int wave = tid >> 6, lane = tid & 63;
    const int b    = blockIdx.x * 4 + wave;
    const bool valid = (lane < T);
    const int jc   = valid ? lane : (T - 1);  // lanes 48..63 duplicate col 47
    float* lds = &Wlds[wave][0];

    // E column in registers: E[i] = exp(trans[i][jc]); then make opaque
    float E[T];
    #pragma unroll
    for (int i = 0; i < T; ++i) E[i] = __expf(trans[i * T + jc]);
    PIN_E(E);

    const float* emb = emissions + (size_t)b * T + jc;   // + t*BATCH*T per step
    const int*   mkb = mask + b;

    // init: alpha0 = start + em[0]; W = exp(alpha0 - alpha0[0]); C = alpha0[0]
    const float a0 = start_tr[jc] + emb[0];
    const float A0 = bcast_lane0(a0);
    float w_self = __expf(a0 - A0);
    float C = A0;
    lds[lane] = w_self;
    float W[T];
    #pragma unroll
    for (int k = 0; k < T / 4; ++k) {
        const float4 v = ((const float4*)lds)[k];
        W[4 * k + 0] = v.x; W[4 * k + 1] = v.y;
        W[4 * k + 2] = v.z; W[4 * k + 3] = v.w;
    }

    // double-buffered 8-deep prefetch, all indices compile-time
    float emA[CHUNK], emB[CHUNK];
    int   mkA[CHUNK], mkB[CHUNK];
    #pragma unroll
    for (int u = 0; u < CHUNK; ++u) {
        const int tt = 1 + u;
        emA[u] = emb[(size_t)tt * (BATCH * T)];
        mkA[u] = mkb[tt * BATCH];
    }

    for (int c = 0; c < NCH; c += 2) {
        {   // issue chunk c+1 -> B
            const int tB = 1 + (c + 1) * CHUNK;
            #pragma unroll
            for (int u = 0; u < CHUNK; ++u) {
                const int tt = tB + u;
                const bool ok = (tt <= LSEQ - 1);
                const int tc = ok ? tt : (LSEQ - 1);
                emB[u] = emb[(size_t)tc * (BATCH * T)];
                mkB[u] = ok ? mkb[tc * BATCH] : 0;
            }
        }
        #pragma unroll
        for (int u = 0; u < CHUNK; ++u)       // compute chunk c from A
            crf_step(W, w_self, C, emA[u], mkA[u], E, lds, lane);
        {   // issue chunk c+2 -> A
            const int tA = 1 + (c + 2) * CHUNK;
            #pragma unroll
            for (int u = 0; u < CHUNK; ++u) {
                const int tt = tA + u;
                const bool ok = (tt <= LSEQ - 1);
                const int tc = ok ? tt : (LSEQ - 1);
                emA[u] = emb[(size_t)tc * (BATCH * T)];
                mkA[u] = ok ? mkb[tc * BATCH] : 0;
            }
        }
        #pragma unroll
        for (int u = 0; u < CHUNK; ++u)       // compute chunk c+1 from B
            crf_step(W, w_self, C, emB[u], mkB[u], E, lds, lane);
    }

    // denominator = C + log( sum_j W[j] * exp(end[j]) );  W[j] == lane j's w_self
    float v = valid ? (w_self * __expf(end_tr[jc])) : 0.f;
    #pragma unroll
    for (int off = 32; off > 0; off >>= 1) v += __shfl_xor(v, off);
    if (lane == 0) denom_out[b] = C + __logf(v);
}

// ---------------------------------------------------------------------------
// Kernel 2: numerator partial sums over t-chunks (runtime chunk count).
// ---------------------------------------------------------------------------
__global__ __launch_bounds__(256) void crf_score_partial(
    const float* __restrict__ emissions,
    const int* __restrict__ tags,             // (L,B)
    const int* __restrict__ mask,             // (L,B)
    const float* __restrict__ trans,          // (T,T)
    float* __restrict__ part,                 // (nchunk, B)
    int* __restrict__ cnt,                    // (nchunk, B)
    int csz)
{
    const int gid = blockIdx.x * blockDim.x + threadIdx.x;
    const int b = gid & (BATCH - 1);
    const int c = gid >> 10;
    const int t0 = c * csz;
    const int t1 = t0 + csz;

    float sc = 0.f;
    int ct = 0;
    const int tstart = (t0 == 0) ? 1 : t0;
    if (t0 == 0) ct += mask[b] ? 1 : 0;       // t = 0 contributes to count only

    int tag_prev = tags[(tstart - 1) * BATCH + b];
    for (int t = tstart; t < t1; ++t) {
        const int tag = tags[t * BATCH + b];
        const int mt = mask[t * BATCH + b];
        if (mt) {
            sc += trans[tag_prev * T + tag]
                + emissions[((size_t)t * BATCH + b) * T + tag];
            ct += 1;
        }
        tag_prev = tag;                       // raw previous tag, per reference
    }
    part[gid] = sc;
    cnt[gid] = ct;
}

// ---------------------------------------------------------------------------
// Kernel 3: combine partials + start/end terms, subtract denominator, mean.
// ---------------------------------------------------------------------------
__global__ __launch_bounds__(1024) void crf_combine(
    const float* __restrict__ emissions,
    const int* __restrict__ tags,
    const float* __restrict__ start_tr,
    const float* __restrict__ end_tr,
    const float* __restrict__ part,
    const int* __restrict__ cnt,
    const float* __restrict__ denom,
    float* __restrict__ out,
    int nchunk)
{
    const int b = threadIdx.x;

    const int tag0 = tags[b];
    float sc = start_tr[tag0] + emissions[(size_t)b * T + tag0];
    int ct = 0;
    for (int c = 0; c < nchunk; ++c) {
        sc += part[c * BATCH + b];
        ct += cnt[c * BATCH + b];
    }
    if (ct < 1) ct = 1;                        // guard (mask all-zero)
    const int last_tag = tags[(ct - 1) * BATCH + b];
    sc += end_tr[last_tag];

    const float llh = sc - denom[b];

    __shared__ float red[1024];
    red[b] = llh;
    __syncthreads();
    #pragma unroll
    for (int s = 512; s > 0; s >>= 1) {
        if (b < s) red[b] += red[b + s];
        __syncthreads();
    }
    if (b == 0) out[0] = red[0] / (float)BATCH;
}

extern "C" void kernel_launch(void* const* d_in, const int* in_sizes, int n_in,
                              void* d_out, int out_size, void* d_ws, size_t ws_size,
                              hipStream_t stream) {
    const float* emissions        = (const float*)d_in[0];
    const int* tags               = (const int*)d_in[1];
    const int* mask               = (const int*)d_in[2];
    const float* start_tr         = (const float*)d_in[3];
    const float* end_tr           = (const float*)d_in[4];
    const float* trans            = (const float*)d_in[5];
    float* out                    = (float*)d_out;

    // scale numerator chunk count to available workspace
    const int nchunk = (ws_size >= (size_t)(BATCH * 4 + 32 * BATCH * 8 + 64)) ? 32 : 8;
    const int csz    = LSEQ / nchunk;

    float* denom = (float*)d_ws;                  // B floats
    float* part  = denom + BATCH;                 // nchunk*B floats
    int*   cnt   = (int*)(part + nchunk * BATCH); // nchunk*B ints

    crf_forward<<<256, 256, 0, stream>>>(emissions, mask, start_tr, end_tr, trans, denom);
    crf_score_partial<<<nchunk * BATCH / 256, 256, 0, stream>>>(
        emissions, tags, mask, trans, part, cnt, csz);
    crf_combine<<<1, 1024, 0, stream>>>(emissions, tags, start_tr, end_tr,
                                        part, cnt, denom, out, nchunk);
}

// Round 9
// 231.643 us; speedup vs baseline: 1.2974x; 1.2974x over previous
//
#include <hip/hip_runtime.h>

#define LSEQ 512
#define BATCH 1024
#define T 48

typedef float f4 __attribute__((ext_vector_type(4)));
typedef __fp16 h2 __attribute__((ext_vector_type(2)));
typedef __fp16 h4 __attribute__((ext_vector_type(4)));
typedef float f32x4 __attribute__((ext_vector_type(4)));

// MFMA wrapper: resolve the builtin ONLY in the device pass; the host pass
// parses kernel bodies too and __has_builtin(amdgcn builtins) is false there.
static __device__ __forceinline__ f32x4 mfma16(h4 a, h4 b, f32x4 c) {
#if defined(__HIP_DEVICE_COMPILE__)
#if __has_builtin(__builtin_amdgcn_mfma_f32_16x16x16f16)
    return __builtin_amdgcn_mfma_f32_16x16x16f16(a, b, c, 0, 0, 0);
#else
    return __builtin_amdgcn_mfma_f32_16x16x16_f16(a, b, c, 0, 0, 0);
#endif
#else
    return c;  // host stub, never executed
#endif
}

static __device__ __forceinline__ h4 pack4(float a, float b, float c, float d) {
    h2 lo = __builtin_amdgcn_cvt_pkrtz(a, b);
    h2 hi = __builtin_amdgcn_cvt_pkrtz(c, d);
    h4 r; r.x = lo.x; r.y = lo.y; r.z = hi.x; r.w = hi.y;
    return r;
}
static __device__ __forceinline__ h4 sel4(bool c, h4 a, h4 b) {
    int2 ai = __builtin_bit_cast(int2, a), bi = __builtin_bit_cast(int2, b);
    int2 r; r.x = c ? ai.x : bi.x; r.y = c ? ai.y : bi.y;
    return __builtin_bit_cast(h4, r);
}
static __device__ __forceinline__ float fast_rcp(float x) {
#if defined(__HIP_DEVICE_COMPILE__) && __has_builtin(__builtin_amdgcn_rcpf)
    return __builtin_amdgcn_rcpf(x);
#else
    return 1.0f / x;
#endif
}

// ---------------------------------------------------------------------------
// Forward algorithm via MFMA. One wave = 16 batches. X(48x16) states x batches.
// Fragments (lane l, col=l&15, g=l>>4), v_mfma_f32_16x16x16_f16 layout:
//   B chunk kc : X[16kc+4g+i][col]        (f16x4)     -- the state matrix
//   A blk rb,kc: M[16rb+row][16kc+k]      row=l&15, k=4g+i, M=E^T,
//                = exp(trans[16kc+4g+i][16rb+(l&15)]) (constant, 18 VGPRs)
//   D blk rb   : Y[16rb+4g+i][col]        (f32x4)
// D-block rb fragment mapping == B-chunk rb mapping  =>  MFMA output feeds the
// next step's B operand directly: no cross-lane data movement in the loop.
// Per step: Y = M.X (9 MFMA); W' = exp(em).Y / N_b, N_b = max_s(exp(em).Y)
// (2 shfl_xor for the cross-g max); C_b += log N_b. alpha = C_b + log W.
// ---------------------------------------------------------------------------
struct Slot { f4 em[3]; int mk; };

__global__ __launch_bounds__(64, 1) void crf_forward(
    const float* __restrict__ emissions,      // (L,B,T)
    const int* __restrict__ mask,             // (L,B) bool->int32
    const float* __restrict__ start_tr,       // (T)
    const float* __restrict__ end_tr,         // (T)
    const float* __restrict__ trans,          // (T,T)
    float* __restrict__ denom_out)            // (B)
{
    const int lane  = threadIdx.x;
    const int col   = lane & 15;
    const int g     = lane >> 4;
    const int bbase = blockIdx.x * 16;
    const int b     = bbase + col;

    // A fragments: constant transition matrix in f16
    h4 Af[3][3];
    #pragma unroll
    for (int rb = 0; rb < 3; ++rb)
        #pragma unroll
        for (int kc = 0; kc < 3; ++kc) {
            float e0 = __expf(trans[(16*kc + 4*g + 0)*T + 16*rb + col]);
            float e1 = __expf(trans[(16*kc + 4*g + 1)*T + 16*rb + col]);
            float e2 = __expf(trans[(16*kc + 4*g + 2)*T + 16*rb + col]);
            float e3 = __expf(trans[(16*kc + 4*g + 3)*T + 16*rb + col]);
            Af[rb][kc] = pack4(e0, e1, e2, e3);
        }

    // ---- init t=0: alpha0 = start + em0; C = max; W = exp(alpha0 - C)
    float a[12];
    #pragma unroll
    for (int kc = 0; kc < 3; ++kc) {
        const f4 em0v = *(const f4*)(emissions + (size_t)b * T + 16*kc + 4*g);
        const f4 st4  = *(const f4*)(start_tr + 16*kc + 4*g);
        #pragma unroll
        for (int i = 0; i < 4; ++i) a[4*kc + i] = st4[i] + em0v[i];
    }
    float m = fmaxf(fmaxf(fmaxf(a[0],a[1]), fmaxf(a[2],a[3])),
              fmaxf(fmaxf(fmaxf(a[4],a[5]), fmaxf(a[6],a[7])),
                    fmaxf(fmaxf(a[8],a[9]), fmaxf(a[10],a[11]))));
    m = fmaxf(m, __shfl_xor(m, 16));
    m = fmaxf(m, __shfl_xor(m, 32));
    float C = m;
    h4 Bf[3];
    #pragma unroll
    for (int kc = 0; kc < 3; ++kc)
        Bf[kc] = pack4(__expf(a[4*kc+0]-m), __expf(a[4*kc+1]-m),
                       __expf(a[4*kc+2]-m), __expf(a[4*kc+3]-m));

    // ---- step lambda
    auto step = [&](const Slot& S) {
        const f32x4 z = {0.f, 0.f, 0.f, 0.f};
        f32x4 D[3];
        #pragma unroll
        for (int rb = 0; rb < 3; ++rb) {
            D[rb] = mfma16(Af[rb][0], Bf[0], z);
            D[rb] = mfma16(Af[rb][1], Bf[1], D[rb]);
            D[rb] = mfma16(Af[rb][2], Bf[2], D[rb]);
        }
        float y[12];
        #pragma unroll
        for (int kc = 0; kc < 3; ++kc)
            #pragma unroll
            for (int i = 0; i < 4; ++i)
                y[4*kc + i] = __expf(S.em[kc][i]) * D[kc][i];
        float mx = fmaxf(fmaxf(fmaxf(y[0],y[1]), fmaxf(y[2],y[3])),
                   fmaxf(fmaxf(fmaxf(y[4],y[5]), fmaxf(y[6],y[7])),
                         fmaxf(fmaxf(y[8],y[9]), fmaxf(y[10],y[11]))));
        mx = fmaxf(mx, __shfl_xor(mx, 16));
        mx = fmaxf(mx, __shfl_xor(mx, 32));
        const float rs = fast_rcp(mx);
        const float lg = __logf(mx);
        const bool upd = (S.mk != 0);
        #pragma unroll
        for (int kc = 0; kc < 3; ++kc)
            Bf[kc] = sel4(upd,
                          pack4(y[4*kc+0]*rs, y[4*kc+1]*rs,
                                y[4*kc+2]*rs, y[4*kc+3]*rs),
                          Bf[kc]);
        C = upd ? (C + lg) : C;
    };

    auto load = [&](Slot& S, int t) {
        const size_t off = ((size_t)t * BATCH + b) * T + 4*g;
        S.em[0] = *(const f4*)(emissions + off);
        S.em[1] = *(const f4*)(emissions + off + 16);
        S.em[2] = *(const f4*)(emissions + off + 32);
        S.mk    = mask[t * BATCH + b];
    };
    auto loadc = [&](Slot& S, int t) { load(S, t > LSEQ-1 ? LSEQ-1 : t); };

    // ---- main loop: steps t=1..511, 4-deep prefetch
    Slot S0, S1, S2, S3;
    load(S0, 1); load(S1, 2); load(S2, 3); load(S3, 4);
    for (int t = 1; t <= LSEQ - 4; t += 4) {       // t = 1,5,...,505
        step(S0); loadc(S0, t + 4);
        step(S1); loadc(S1, t + 5);
        step(S2); loadc(S2, t + 6);
        step(S3); loadc(S3, t + 7);
    }
    step(S0); step(S1); step(S2);                  // t = 509, 510, 511

    // ---- denominator_b = C + log( sum_s W[s][b] * exp(end[s]) )
    float v = 0.f;
    #pragma unroll
    for (int kc = 0; kc < 3; ++kc) {
        const f4 endv = *(const f4*)(end_tr + 16*kc + 4*g);
        #pragma unroll
        for (int i = 0; i < 4; ++i)
            v += (float)Bf[kc][i] * __expf(endv[i]);
    }
    v += __shfl_xor(v, 16);
    v += __shfl_xor(v, 32);
    if (lane < 16) denom_out[bbase + lane] = C + __logf(v);
}

// ---------------------------------------------------------------------------
// Kernel 2: numerator partial sums over t-chunks (runtime chunk count).
// ---------------------------------------------------------------------------
__global__ __launch_bounds__(256) void crf_score_partial(
    const float* __restrict__ emissions,
    const int* __restrict__ tags,             // (L,B)
    const int* __restrict__ mask,             // (L,B)
    const float* __restrict__ trans,          // (T,T)
    float* __restrict__ part,                 // (nchunk, B)
    int* __restrict__ cnt,                    // (nchunk, B)
    int csz)
{
    const int gid = blockIdx.x * blockDim.x + threadIdx.x;
    const int b = gid & (BATCH - 1);
    const int c = gid >> 10;
    const int t0 = c * csz;
    const int t1 = t0 + csz;

    float sc = 0.f;
    int ct = 0;
    const int tstart = (t0 == 0) ? 1 : t0;
    if (t0 == 0) ct += mask[b] ? 1 : 0;       // t = 0 contributes to count only

    int tag_prev = tags[(tstart - 1) * BATCH + b];
    for (int t = tstart; t < t1; ++t) {
        const int tag = tags[t * BATCH + b];
        const int mt = mask[t * BATCH + b];
        if (mt) {
            sc += trans[tag_prev * T + tag]
                + emissions[((size_t)t * BATCH + b) * T + tag];
            ct += 1;
        }
        tag_prev = tag;                       // raw previous tag, per reference
    }
    part[gid] = sc;
    cnt[gid] = ct;
}

// ---------------------------------------------------------------------------
// Kernel 3: combine partials + start/end terms, subtract denominator, mean.
// ---------------------------------------------------------------------------
__global__ __launch_bounds__(1024) void crf_combine(
    const float* __restrict__ emissions,
    const int* __restrict__ tags,
    const float* __restrict__ start_tr,
    const float* __restrict__ end_tr,
    const float* __restrict__ part,
    const int* __restrict__ cnt,
    const float* __restrict__ denom,
    float* __restrict__ out,
    int nchunk)
{
    const int b = threadIdx.x;

    const int tag0 = tags[b];
    float sc = start_tr[tag0] + emissions[(size_t)b * T + tag0];
    int ct = 0;
    for (int c = 0; c < nchunk; ++c) {
        sc += part[c * BATCH + b];
        ct += cnt[c * BATCH + b];
    }
    if (ct < 1) ct = 1;                        // guard (mask all-zero)
    const int last_tag = tags[(ct - 1) * BATCH + b];
    sc += end_tr[last_tag];

    const float llh = sc - denom[b];

    __shared__ float red[1024];
    red[b] = llh;
    __syncthreads();
    #pragma unroll
    for (int s = 512; s > 0; s >>= 1) {
        if (b < s) red[b] += red[b + s];
        __syncthreads();
    }
    if (b == 0) out[0] = red[0] / (float)BATCH;
}

extern "C" void kernel_launch(void* const* d_in, const int* in_sizes, int n_in,
                              void* d_out, int out_size, void* d_ws, size_t ws_size,
                              hipStream_t stream) {
    const float* emissions        = (const float*)d_in[0];
    const int* tags               = (const int*)d_in[1];
    const int* mask               = (const int*)d_in[2];
    const float* start_tr         = (const float*)d_in[3];
    const float* end_tr           = (const float*)d_in[4];
    const float* trans            = (const float*)d_in[5];
    float* out                    = (float*)d_out;

    // scale numerator chunk count to available workspace
    const int nchunk = (ws_size >= (size_t)(BATCH * 4 + 32 * BATCH * 8 + 64)) ? 32 : 8;
    const int csz    = LSEQ / nchunk;

    float* denom = (float*)d_ws;                  // B floats
    float* part  = denom + BATCH;                 // nchunk*B floats
    int*   cnt   = (int*)(part + nchunk * BATCH); // nchunk*B ints

    crf_forward<<<BATCH / 16, 64, 0, stream>>>(emissions, mask, start_tr,
                                               end_tr, trans, denom);
    crf_score_partial<<<nchunk * BATCH / 256, 256, 0, stream>>>(
        emissions, tags, mask, trans, part, cnt, csz);
    crf_combine<<<1, 1024, 0, stream>>>(emissions, tags, start_tr, end_tr,
                                        part, cnt, denom, out, nchunk);
}

// Round 11
// 226.754 us; speedup vs baseline: 1.3254x; 1.0216x over previous
//
#include <hip/hip_runtime.h>

#define LSEQ 512
#define BATCH 1024
#define T 48
#define SLOTS 6

typedef float f4 __attribute__((ext_vector_type(4)));
typedef __fp16 h2 __attribute__((ext_vector_type(2)));
typedef __fp16 h4 __attribute__((ext_vector_type(4)));
typedef float f32x4 __attribute__((ext_vector_type(4)));

// MFMA wrapper: resolve builtin only in the device pass (host pass parses too)
static __device__ __forceinline__ f32x4 mfma16(h4 a, h4 b, f32x4 c) {
#if defined(__HIP_DEVICE_COMPILE__)
#if __has_builtin(__builtin_amdgcn_mfma_f32_16x16x16f16)
    return __builtin_amdgcn_mfma_f32_16x16x16f16(a, b, c, 0, 0, 0);
#else
    return __builtin_amdgcn_mfma_f32_16x16x16_f16(a, b, c, 0, 0, 0);
#endif
#else
    return c;
#endif
}
static __device__ __forceinline__ void sbar0() {
#if defined(__HIP_DEVICE_COMPILE__)
    __builtin_amdgcn_sched_barrier(0);
#endif
}
// async global->LDS: data lands in LDS, counted by vmcnt. No register hazard.
static __device__ __forceinline__ void gll16(const float* g, float* l) {
#if defined(__HIP_DEVICE_COMPILE__)
    __builtin_amdgcn_global_load_lds(
        (const __attribute__((address_space(1))) unsigned int*)g,
        (__attribute__((address_space(3))) unsigned int*)l, 16, 0, 0);
#endif
}
static __device__ __forceinline__ void gll4(const int* g, int* l) {
#if defined(__HIP_DEVICE_COMPILE__)
    __builtin_amdgcn_global_load_lds(
        (const __attribute__((address_space(1))) unsigned int*)g,
        (__attribute__((address_space(3))) unsigned int*)l, 4, 0, 0);
#endif
}
#define WAITV(N) do { asm volatile("s_waitcnt vmcnt(" #N ")" ::: "memory"); sbar0(); } while (0)

static __device__ __forceinline__ h4 pack4(float a, float b, float c, float d) {
    h2 lo = __builtin_amdgcn_cvt_pkrtz(a, b);
    h2 hi = __builtin_amdgcn_cvt_pkrtz(c, d);
    h4 r; r.x = lo.x; r.y = lo.y; r.z = hi.x; r.w = hi.y;
    return r;
}
static __device__ __forceinline__ h4 sel4(bool c, h4 a, h4 b) {
    int2 ai = __builtin_bit_cast(int2, a), bi = __builtin_bit_cast(int2, b);
    int2 r; r.x = c ? ai.x : bi.x; r.y = c ? ai.y : bi.y;
    return __builtin_bit_cast(h4, r);
}
static __device__ __forceinline__ float fast_rcp(float x) {
#if defined(__HIP_DEVICE_COMPILE__) && __has_builtin(__builtin_amdgcn_rcpf)
    return __builtin_amdgcn_rcpf(x);
#else
    return 1.0f / x;
#endif
}

// ---------------------------------------------------------------------------
// Forward algorithm via MFMA (fragment layout verified: absmax 0.0, round 9).
// One wave = 16 batches. Per step: Y = M.X (9 chained 16x16x16 f16 MFMA),
// W' = exp(em).Y / max, C += log max; D-fragment == next B-fragment (in-VGPR
// recurrence). Memory: 6-slot rotating LDS file filled by global_load_lds
// (4 vmcnt units/slot), consumed under counted s_waitcnt vmcnt(20) —
// never drained in-loop. exp(em_{t+1}) precomputed during step t.
// ---------------------------------------------------------------------------
__global__ __launch_bounds__(64, 1) void crf_forward(
    const float* __restrict__ emissions,      // (L,B,T)
    const int* __restrict__ mask,             // (L,B) bool->int32
    const float* __restrict__ start_tr,       // (T)
    const float* __restrict__ end_tr,         // (T)
    const float* __restrict__ trans,          // (T,T)
    float* __restrict__ denom_out)            // (B)
{
    __shared__ __align__(16) float em_lds[SLOTS][3][64][4];   // 18 KB
    __shared__ int mk_lds[SLOTS][64];                         // 1.5 KB

    const int lane  = threadIdx.x;
    const int col   = lane & 15;
    const int g     = lane >> 4;
    const int bbase = blockIdx.x * 16;
    const int b     = bbase + col;

    // A fragments: M = E^T in f16 (constant, 18 VGPRs)
    h4 Af[3][3];
    #pragma unroll
    for (int rb = 0; rb < 3; ++rb)
        #pragma unroll
        for (int kc = 0; kc < 3; ++kc) {
            float e0 = __expf(trans[(16*kc + 4*g + 0)*T + 16*rb + col]);
            float e1 = __expf(trans[(16*kc + 4*g + 1)*T + 16*rb + col]);
            float e2 = __expf(trans[(16*kc + 4*g + 2)*T + 16*rb + col]);
            float e3 = __expf(trans[(16*kc + 4*g + 3)*T + 16*rb + col]);
            Af[rb][kc] = pack4(e0, e1, e2, e3);
        }

    // init t=0 (plain loads, fully consumed below)
    float a[12];
    #pragma unroll
    for (int kc = 0; kc < 3; ++kc) {
        const f4 em0v = *(const f4*)(emissions + (size_t)b * T + 16*kc + 4*g);
        const f4 st4  = *(const f4*)(start_tr + 16*kc + 4*g);
        #pragma unroll
        for (int i = 0; i < 4; ++i) a[4*kc + i] = st4[i] + em0v[i];
    }
    float m = fmaxf(fmaxf(fmaxf(a[0],a[1]), fmaxf(a[2],a[3])),
              fmaxf(fmaxf(fmaxf(a[4],a[5]), fmaxf(a[6],a[7])),
                    fmaxf(fmaxf(a[8],a[9]), fmaxf(a[10],a[11]))));
    m = fmaxf(m, __shfl_xor(m, 16));
    m = fmaxf(m, __shfl_xor(m, 32));
    float C = m;
    h4 Bf[3];
    #pragma unroll
    for (int kc = 0; kc < 3; ++kc)
        Bf[kc] = pack4(__expf(a[4*kc+0]-m), __expf(a[4*kc+1]-m),
                       __expf(a[4*kc+2]-m), __expf(a[4*kc+3]-m));

    // drain ALL prologue vector loads so vmcnt counts only our GLLs
    asm volatile("s_waitcnt vmcnt(0)" ::: "memory");
    sbar0();

    // ---- slot file ------------------------------------------------------
    auto issue_slot = [&](int s, int t) {
        const int tl = t > LSEQ-1 ? LSEQ-1 : t;
        const float* gp = emissions + ((size_t)tl * BATCH + b) * T + 4*g;
        gll16(gp,      &em_lds[s][0][0][0]);   // per-lane src, lane*16 dest
        gll16(gp + 16, &em_lds[s][1][0][0]);
        gll16(gp + 32, &em_lds[s][2][0][0]);
        gll4(mask + tl * BATCH + b, &mk_lds[s][0]);
    };

    issue_slot(0, 1); issue_slot(1, 2); issue_slot(2, 3);
    issue_slot(3, 4); issue_slot(4, 5); issue_slot(5, 6);   // 24 in flight
    WAITV(20);                                              // slot 0 landed
    f4 pexpc[3]; int mkc;
    {
        #pragma unroll
        for (int kc = 0; kc < 3; ++kc) {
            const f4 v = *(const f4*)&em_lds[0][kc][lane][0];
            #pragma unroll
            for (int i = 0; i < 4; ++i) pexpc[kc][i] = __expf(v[i]);
        }
        mkc = mk_lds[0][lane];
    }

    // body at step t: re-issue the slot just consumed (t+6), wait for slot
    // t+1, precompute its exps, run the MFMA step with pexpc/mkc (slot t).
    auto body = [&](int t, int s_reuse, int s_next) {
        issue_slot(s_reuse, t + 6);
        WAITV(20);                             // slot t+1 complete in LDS
        f4 pn[3];
        #pragma unroll
        for (int kc = 0; kc < 3; ++kc) {
            const f4 v = *(const f4*)&em_lds[s_next][kc][lane][0];
            #pragma unroll
            for (int i = 0; i < 4; ++i) pn[kc][i] = __expf(v[i]);
        }
        const int mkn = mk_lds[s_next][lane];

        const f32x4 z = {0.f, 0.f, 0.f, 0.f};
        f32x4 D[3];
        #pragma unroll
        for (int rb = 0; rb < 3; ++rb) {
            D[rb] = mfma16(Af[rb][0], Bf[0], z);
            D[rb] = mfma16(Af[rb][1], Bf[1], D[rb]);
            D[rb] = mfma16(Af[rb][2], Bf[2], D[rb]);
        }
        float y[12];
        #pragma unroll
        for (int kc = 0; kc < 3; ++kc)
            #pragma unroll
            for (int i = 0; i < 4; ++i)
                y[4*kc + i] = pexpc[kc][i] * D[kc][i];
        float mx = fmaxf(fmaxf(fmaxf(y[0],y[1]), fmaxf(y[2],y[3])),
                   fmaxf(fmaxf(fmaxf(y[4],y[5]), fmaxf(y[6],y[7])),
                         fmaxf(fmaxf(y[8],y[9]), fmaxf(y[10],y[11]))));
        mx = fmaxf(mx, __shfl_xor(mx, 16));
        mx = fmaxf(mx, __shfl_xor(mx, 32));
        const float rs = fast_rcp(mx);
        const float lg = __logf(mx);
        const bool upd = (mkc != 0) && (t <= LSEQ - 1);
        #pragma unroll
        for (int kc = 0; kc < 3; ++kc)
            Bf[kc] = sel4(upd,
                          pack4(y[4*kc+0]*rs, y[4*kc+1]*rs,
                                y[4*kc+2]*rs, y[4*kc+3]*rs),
                          Bf[kc]);
        C = upd ? (C + lg) : C;
        pexpc[0] = pn[0]; pexpc[1] = pn[1]; pexpc[2] = pn[2]; mkc = mkn;
    };

    // t = 1..511 real steps; trailing ghost steps (512..516) are mask-gated
    for (int t0 = 1; t0 <= LSEQ - 1; t0 += 6) {
        body(t0 + 0, 0, 1);
        body(t0 + 1, 1, 2);
        body(t0 + 2, 2, 3);
        body(t0 + 3, 3, 4);
        body(t0 + 4, 4, 5);
        body(t0 + 5, 5, 0);
    }

    // denominator_b = C + log( sum_s W[s][b] * exp(end[s]) )
    float v = 0.f;
    #pragma unroll
    for (int kc = 0; kc < 3; ++kc) {
        const f4 endv = *(const f4*)(end_tr + 16*kc + 4*g);
        #pragma unroll
        for (int i = 0; i < 4; ++i)
            v += (float)Bf[kc][i] * __expf(endv[i]);
    }
    v += __shfl_xor(v, 16);
    v += __shfl_xor(v, 32);
    if (lane < 16) denom_out[bbase + lane] = C + __logf(v);
}

// ---------------------------------------------------------------------------
// Kernel 2: numerator partial sums over t-chunks (runtime chunk count).
// ---------------------------------------------------------------------------
__global__ __launch_bounds__(256) void crf_score_partial(
    const float* __restrict__ emissions,
    const int* __restrict__ tags,             // (L,B)
    const int* __restrict__ mask,             // (L,B)
    const float* __restrict__ trans,          // (T,T)
    float* __restrict__ part,                 // (nchunk, B)
    int* __restrict__ cnt,                    // (nchunk, B)
    int csz)
{
    const int gid = blockIdx.x * blockDim.x + threadIdx.x;
    const int b = gid & (BATCH - 1);
    const int c = gid >> 10;
    const int t0 = c * csz;
    const int t1 = t0 + csz;

    float sc = 0.f;
    int ct = 0;
    const int tstart = (t0 == 0) ? 1 : t0;
    if (t0 == 0) ct += mask[b] ? 1 : 0;       // t = 0 contributes to count only

    int tag_prev = tags[(tstart - 1) * BATCH + b];
    for (int t = tstart; t < t1; ++t) {
        const int tag = tags[t * BATCH + b];
        const int mt = mask[t * BATCH + b];
        if (mt) {
            sc += trans[tag_prev * T + tag]
                + emissions[((size_t)t * BATCH + b) * T + tag];
            ct += 1;
        }
        tag_prev = tag;                       // raw previous tag, per reference
    }
    part[gid] = sc;
    cnt[gid] = ct;
}

// ---------------------------------------------------------------------------
// Kernel 3: combine partials + start/end terms, subtract denominator, mean.
// ---------------------------------------------------------------------------
__global__ __launch_bounds__(1024) void crf_combine(
    const float* __restrict__ emissions,
    const int* __restrict__ tags,
    const float* __restrict__ start_tr,
    const float* __restrict__ end_tr,
    const float* __restrict__ part,
    const int* __restrict__ cnt,
    const float* __restrict__ denom,
    float* __restrict__ out,
    int nchunk)
{
    const int b = threadIdx.x;

    const int tag0 = tags[b];
    float sc = start_tr[tag0] + emissions[(size_t)b * T + tag0];
    int ct = 0;
    for (int c = 0; c < nchunk; ++c) {
        sc += part[c * BATCH + b];
        ct += cnt[c * BATCH + b];
    }
    if (ct < 1) ct = 1;                        // guard (mask all-zero)
    const int last_tag = tags[(ct - 1) * BATCH + b];
    sc += end_tr[last_tag];

    const float llh = sc - denom[b];

    __shared__ float red[1024];
    red[b] = llh;
    __syncthreads();
    #pragma unroll
    for (int s = 512; s > 0; s >>= 1) {
        if (b < s) red[b] += red[b + s];
        __syncthreads();
    }
    if (b == 0) out[0] = red[0] / (float)BATCH;
}

extern "C" void kernel_launch(void* const* d_in, const int* in_sizes, int n_in,
                              void* d_out, int out_size, void* d_ws, size_t ws_size,
                              hipStream_t stream) {
    const float* emissions        = (const float*)d_in[0];
    const int* tags               = (const int*)d_in[1];
    const int* mask               = (const int*)d_in[2];
    const float* start_tr         = (const float*)d_in[3];
    const float* end_tr           = (const float*)d_in[4];
    const float* trans            = (const float*)d_in[5];
    float* out                    = (float*)d_out;

    // scale numerator chunk count to available workspace
    const int nchunk = (ws_size >= (size_t)(BATCH * 4 + 32 * BATCH * 8 + 64)) ? 32 : 8;
    const int csz    = LSEQ / nchunk;

    float* denom = (float*)d_ws;                  // B floats
    float* part  = denom + BATCH;                 // nchunk*B floats
    int*   cnt   = (int*)(part + nchunk * BATCH); // nchunk*B ints

    crf_forward<<<BATCH / 16, 64, 0, stream>>>(emissions, mask, start_tr,
                                               end_tr, trans, denom);
    crf_score_partial<<<nchunk * BATCH / 256, 256, 0, stream>>>(
        emissions, tags, mask, trans, part, cnt, csz);
    crf_combine<<<1, 1024, 0, stream>>>(emissions, tags, start_tr, end_tr,
                                        part, cnt, denom, out, nchunk);
}

// Round 12
// 204.103 us; speedup vs baseline: 1.4725x; 1.1110x over previous
//
#include <hip/hip_runtime.h>

#define LSEQ 512
#define BATCH 1024
#define T 48

typedef float f4 __attribute__((ext_vector_type(4)));
typedef __fp16 h2 __attribute__((ext_vector_type(2)));
typedef __fp16 h4 __attribute__((ext_vector_type(4)));
typedef float f32x4 __attribute__((ext_vector_type(4)));

// MFMA wrapper: resolve builtin only in the device pass (host pass parses too)
static __device__ __forceinline__ f32x4 mfma16(h4 a, h4 b, f32x4 c) {
#if defined(__HIP_DEVICE_COMPILE__)
#if __has_builtin(__builtin_amdgcn_mfma_f32_16x16x16f16)
    return __builtin_amdgcn_mfma_f32_16x16x16f16(a, b, c, 0, 0, 0);
#else
    return __builtin_amdgcn_mfma_f32_16x16x16_f16(a, b, c, 0, 0, 0);
#endif
#else
    return c;
#endif
}
static __device__ __forceinline__ void sbar0() {
#if defined(__HIP_DEVICE_COMPILE__)
    __builtin_amdgcn_sched_barrier(0);   // nothing crosses, either direction
#endif
}
static __device__ __forceinline__ h4 pack4(float a, float b, float c, float d) {
    h2 lo = __builtin_amdgcn_cvt_pkrtz(a, b);
    h2 hi = __builtin_amdgcn_cvt_pkrtz(c, d);
    h4 r; r.x = lo.x; r.y = lo.y; r.z = hi.x; r.w = hi.y;
    return r;
}
static __device__ __forceinline__ h4 sel4(bool c, h4 a, h4 b) {
    int2 ai = __builtin_bit_cast(int2, a), bi = __builtin_bit_cast(int2, b);
    int2 r; r.x = c ? ai.x : bi.x; r.y = c ? ai.y : bi.y;
    return __builtin_bit_cast(h4, r);
}
static __device__ __forceinline__ float fast_rcp(float x) {
#if defined(__HIP_DEVICE_COMPILE__) && __has_builtin(__builtin_amdgcn_rcpf)
    return __builtin_amdgcn_rcpf(x);
#else
    return 1.0f / x;
#endif
}

// ---------------------------------------------------------------------------
// Forward algorithm via MFMA (fragment layout verified: absmax 0.0, r9 & r11).
// One wave = 16 batches. Per step: Y = M.X (9 chained 16x16x16 f16 MFMA),
// W' = exp(em).Y / max, C += log max; D-fragment == next B-fragment (in-VGPR
// recurrence).
// Memory: 6 NAMED register slots (plain loads -> precise per-register
// compiler waitcnts, no LDS aliasing), each issue block fenced by
// sched_barrier(0) so loads can neither sink nor hoist (r4/r9 failure mode),
// giving a true 6-step-deep pipeline (~>1200 cyc issue-to-use).
// exp(em_{t+1}) is precomputed during step t in ping-pong buffers.
// ---------------------------------------------------------------------------
struct Slot { f4 em0, em1, em2; int mk; };

__global__ __launch_bounds__(64, 1) void crf_forward(
    const float* __restrict__ emissions,      // (L,B,T)
    const int* __restrict__ mask,             // (L,B) bool->int32
    const float* __restrict__ start_tr,       // (T)
    const float* __restrict__ end_tr,         // (T)
    const float* __restrict__ trans,          // (T,T)
    float* __restrict__ denom_out)            // (B)
{
    const int lane  = threadIdx.x;
    const int col   = lane & 15;
    const int g     = lane >> 4;
    const int bbase = blockIdx.x * 16;
    const int b     = bbase + col;

    // A fragments: M = E^T in f16 (constant, 18 VGPRs)
    h4 Af[3][3];
    #pragma unroll
    for (int rb = 0; rb < 3; ++rb)
        #pragma unroll
        for (int kc = 0; kc < 3; ++kc) {
            float e0 = __expf(trans[(16*kc + 4*g + 0)*T + 16*rb + col]);
            float e1 = __expf(trans[(16*kc + 4*g + 1)*T + 16*rb + col]);
            float e2 = __expf(trans[(16*kc + 4*g + 2)*T + 16*rb + col]);
            float e3 = __expf(trans[(16*kc + 4*g + 3)*T + 16*rb + col]);
            Af[rb][kc] = pack4(e0, e1, e2, e3);
        }

    // init t=0
    float a[12];
    #pragma unroll
    for (int kc = 0; kc < 3; ++kc) {
        const f4 em0v = *(const f4*)(emissions + (size_t)b * T + 16*kc + 4*g);
        const f4 st4  = *(const f4*)(start_tr + 16*kc + 4*g);
        #pragma unroll
        for (int i = 0; i < 4; ++i) a[4*kc + i] = st4[i] + em0v[i];
    }
    float m = fmaxf(fmaxf(fmaxf(a[0],a[1]), fmaxf(a[2],a[3])),
              fmaxf(fmaxf(fmaxf(a[4],a[5]), fmaxf(a[6],a[7])),
                    fmaxf(fmaxf(a[8],a[9]), fmaxf(a[10],a[11]))));
    m = fmaxf(m, __shfl_xor(m, 16));
    m = fmaxf(m, __shfl_xor(m, 32));
    float C = m;
    h4 Bf[3];
    #pragma unroll
    for (int kc = 0; kc < 3; ++kc)
        Bf[kc] = pack4(__expf(a[4*kc+0]-m), __expf(a[4*kc+1]-m),
                       __expf(a[4*kc+2]-m), __expf(a[4*kc+3]-m));

    // ---- 6-deep named register slot file --------------------------------
    Slot S0, S1, S2, S3, S4, S5;
    auto issue = [&](Slot& S, int t) {
        const int tl = t > LSEQ-1 ? LSEQ-1 : t;
        const float* p = emissions + ((size_t)tl * BATCH + b) * T + 4*g;
        S.em0 = *(const f4*)p;
        S.em1 = *(const f4*)(p + 16);
        S.em2 = *(const f4*)(p + 32);
        S.mk  = mask[tl * BATCH + b];
    };

    issue(S0, 1); issue(S1, 2); issue(S2, 3);
    issue(S3, 4); issue(S4, 5); issue(S5, 6);
    sbar0();                                   // pin prologue issue block

    f4 pexpA[3], pexpB[3];  int mkA_, mkB_;
    #pragma unroll
    for (int i = 0; i < 4; ++i) {
        pexpA[0][i] = __expf(S0.em0[i]);       // compiler waits S0 (counted)
        pexpA[1][i] = __expf(S0.em1[i]);
        pexpA[2][i] = __expf(S0.em2[i]);
    }
    mkA_ = S0.mk;

    // body at step t: issue slot t+6 (fenced), precompute exps of slot t+1
    // into pn, run the MFMA step with pc (slot t).
    auto body = [&](int t, Slot& Sload, Slot& Snext,
                    f4* pc, int& mc, f4* pn, int& mn) {
        issue(Sload, t + 6);
        sbar0();                               // issue point fixed here
        #pragma unroll
        for (int i = 0; i < 4; ++i) {
            pn[0][i] = __expf(Snext.em0[i]);   // counted vmcnt wait (~20)
            pn[1][i] = __expf(Snext.em1[i]);
            pn[2][i] = __expf(Snext.em2[i]);
        }
        mn = Snext.mk;

        const f32x4 z = {0.f, 0.f, 0.f, 0.f};
        f32x4 D[3];
        #pragma unroll
        for (int rb = 0; rb < 3; ++rb) {
            D[rb] = mfma16(Af[rb][0], Bf[0], z);
            D[rb] = mfma16(Af[rb][1], Bf[1], D[rb]);
            D[rb] = mfma16(Af[rb][2], Bf[2], D[rb]);
        }
        float y[12];
        #pragma unroll
        for (int kc = 0; kc < 3; ++kc)
            #pragma unroll
            for (int i = 0; i < 4; ++i)
                y[4*kc + i] = pc[kc][i] * D[kc][i];
        float mx = fmaxf(fmaxf(fmaxf(y[0],y[1]), fmaxf(y[2],y[3])),
                   fmaxf(fmaxf(fmaxf(y[4],y[5]), fmaxf(y[6],y[7])),
                         fmaxf(fmaxf(y[8],y[9]), fmaxf(y[10],y[11]))));
        mx = fmaxf(mx, __shfl_xor(mx, 16));
        mx = fmaxf(mx, __shfl_xor(mx, 32));
        const float rs = fast_rcp(mx);
        const float lg = __logf(mx);
        const bool upd = (mc != 0) && (t <= LSEQ - 1);
        #pragma unroll
        for (int kc = 0; kc < 3; ++kc)
            Bf[kc] = sel4(upd,
                          pack4(y[4*kc+0]*rs, y[4*kc+1]*rs,
                                y[4*kc+2]*rs, y[4*kc+3]*rs),
                          Bf[kc]);
        C = upd ? (C + lg) : C;
    };

    // t = 1..511 real steps; trailing ghost steps (512..516) are gated off
    for (int t0 = 1; t0 <= LSEQ - 1; t0 += 6) {
        body(t0 + 0, S0, S1, pexpA, mkA_, pexpB, mkB_);
        body(t0 + 1, S1, S2, pexpB, mkB_, pexpA, mkA_);
        body(t0 + 2, S2, S3, pexpA, mkA_, pexpB, mkB_);
        body(t0 + 3, S3, S4, pexpB, mkB_, pexpA, mkA_);
        body(t0 + 4, S4, S5, pexpA, mkA_, pexpB, mkB_);
        body(t0 + 5, S5, S0, pexpB, mkB_, pexpA, mkA_);
    }

    // denominator_b = C + log( sum_s W[s][b] * exp(end[s]) )
    float v = 0.f;
    #pragma unroll
    for (int kc = 0; kc < 3; ++kc) {
        const f4 endv = *(const f4*)(end_tr + 16*kc + 4*g);
        #pragma unroll
        for (int i = 0; i < 4; ++i)
            v += (float)Bf[kc][i] * __expf(endv[i]);
    }
    v += __shfl_xor(v, 16);
    v += __shfl_xor(v, 32);
    if (lane < 16) denom_out[bbase + lane] = C + __logf(v);
}

// ---------------------------------------------------------------------------
// Kernel 2: numerator partial sums over t-chunks (runtime chunk count).
// ---------------------------------------------------------------------------
__global__ __launch_bounds__(256) void crf_score_partial(
    const float* __restrict__ emissions,
    const int* __restrict__ tags,             // (L,B)
    const int* __restrict__ mask,             // (L,B)
    const float* __restrict__ trans,          // (T,T)
    float* __restrict__ part,                 // (nchunk, B)
    int* __restrict__ cnt,                    // (nchunk, B)
    int csz)
{
    const int gid = blockIdx.x * blockDim.x + threadIdx.x;
    const int b = gid & (BATCH - 1);
    const int c = gid >> 10;
    const int t0 = c * csz;
    const int t1 = t0 + csz;

    float sc = 0.f;
    int ct = 0;
    const int tstart = (t0 == 0) ? 1 : t0;
    if (t0 == 0) ct += mask[b] ? 1 : 0;       // t = 0 contributes to count only

    int tag_prev = tags[(tstart - 1) * BATCH + b];
    for (int t = tstart; t < t1; ++t) {
        const int tag = tags[t * BATCH + b];
        const int mt = mask[t * BATCH + b];
        if (mt) {
            sc += trans[tag_prev * T + tag]
                + emissions[((size_t)t * BATCH + b) * T + tag];
            ct += 1;
        }
        tag_prev = tag;                       // raw previous tag, per reference
    }
    part[gid] = sc;
    cnt[gid] = ct;
}

// ---------------------------------------------------------------------------
// Kernel 3: combine partials + start/end terms, subtract denominator, mean.
// ---------------------------------------------------------------------------
__global__ __launch_bounds__(1024) void crf_combine(
    const float* __restrict__ emissions,
    const int* __restrict__ tags,
    const float* __restrict__ start_tr,
    const float* __restrict__ end_tr,
    const float* __restrict__ part,
    const int* __restrict__ cnt,
    const float* __restrict__ denom,
    float* __restrict__ out,
    int nchunk)
{
    const int b = threadIdx.x;

    const int tag0 = tags[b];
    float sc = start_tr[tag0] + emissions[(size_t)b * T + tag0];
    int ct = 0;
    for (int c = 0; c < nchunk; ++c) {
        sc += part[c * BATCH + b];
        ct += cnt[c * BATCH + b];
    }
    if (ct < 1) ct = 1;                        // guard (mask all-zero)
    const int last_tag = tags[(ct - 1) * BATCH + b];
    sc += end_tr[last_tag];

    const float llh = sc - denom[b];

    __shared__ float red[1024];
    red[b] = llh;
    __syncthreads();
    #pragma unroll
    for (int s = 512; s > 0; s >>= 1) {
        if (b < s) red[b] += red[b + s];
        __syncthreads();
    }
    if (b == 0) out[0] = red[0] / (float)BATCH;
}

extern "C" void kernel_launch(void* const* d_in, const int* in_sizes, int n_in,
                              void* d_out, int out_size, void* d_ws, size_t ws_size,
                              hipStream_t stream) {
    const float* emissions        = (const float*)d_in[0];
    const int* tags               = (const int*)d_in[1];
    const int* mask               = (const int*)d_in[2];
    const float* start_tr         = (const float*)d_in[3];
    const float* end_tr           = (const float*)d_in[4];
    const float* trans            = (const float*)d_in[5];
    float* out                    = (float*)d_out;

    // scale numerator chunk count to available workspace
    const int nchunk = (ws_size >= (size_t)(BATCH * 4 + 32 * BATCH * 8 + 64)) ? 32 : 8;
    const int csz    = LSEQ / nchunk;

    float* denom = (float*)d_ws;                  // B floats
    float* part  = denom + BATCH;                 // nchunk*B floats
    int*   cnt   = (int*)(part + nchunk * BATCH); // nchunk*B ints

    crf_forward<<<BATCH / 16, 64, 0, stream>>>(emissions, mask, start_tr,
                                               end_tr, trans, denom);
    crf_score_partial<<<nchunk * BATCH / 256, 256, 0, stream>>>(
        emissions, tags, mask, trans, part, cnt, csz);
    crf_combine<<<1, 1024, 0, stream>>>(emissions, tags, start_tr, end_tr,
                                        part, cnt, denom, out, nchunk);
}